// Round 18
// baseline (241.460 us; speedup 1.0000x reference)
//
#include <hip/hip_runtime.h>
#include <cstdint>
#include <cstddef>

#define B_DIM 16
#define C_DIM 512
#define D_DIM 512
#define N_DIM 2048
#define NSLOTS 512   // BN partial slots per channel: (bz, by, wc) = 16*16*2

typedef _Float16 half8  __attribute__((ext_vector_type(8)));
typedef _Float16 half4v __attribute__((ext_vector_type(4)));
typedef float    floatx4 __attribute__((ext_vector_type(4)));

__device__ __forceinline__ void gload_lds16(const _Float16* g, _Float16* l)
{
    // async global->LDS, 16B per lane. LDS dest = wave-uniform base + lane*16 (linear).
    __builtin_amdgcn_global_load_lds((const __attribute__((address_space(1))) void*)g,
                                     (__attribute__((address_space(3))) void*)l,
                                     16, 0, 0);
}

// ---------------------------------------------------------------------------
// 128x128 2-phase NT GEMM (R4/R11-verified). See R17 comments.
// EPI==1: C = beta*acc + (float)H.   EPI==2: + BN partials [d][p].
// TRI==1: symmetric C, triangle + coalesced mirror.
// ---------------------------------------------------------------------------
template<int EPI, int TRI, typename OutT>
__global__ __launch_bounds__(256, 4)
void gemm_nt(const _Float16* __restrict__ A, size_t strideA,
             const _Float16* __restrict__ Bm, size_t strideB,
             OutT* __restrict__ Cm, size_t strideC,
             int M, int Ncols, int K,
             const float* __restrict__ beta_ptr,
             const _Float16* __restrict__ Hm, size_t strideH,
             float* __restrict__ st_s, float* __restrict__ st_ss)
{
    constexpr int BK  = 64;
    constexpr int TP  = 136;
    constexpr int SMEM_HALFS = TRI ? (128 * TP) : (128 * 2 * BK);
    __shared__ _Float16 smem[SMEM_HALFS];
    _Float16* sA = smem;
    _Float16* sB = smem + 128 * BK;

    const int gx = gridDim.x, gy = gridDim.y;
    const int nwg = gx * gy * gridDim.z;
    int flat = blockIdx.x + gx * (blockIdx.y + gy * blockIdx.z);
    const int q8 = nwg >> 3;
    flat = (flat & 7) * q8 + (flat >> 3);

    int bx, by, bz;
    if (TRI) {
        int tri = flat % gx;
        bz = flat / gx;
        const int nt = Ncols >> 7;
        int r = 0;
        while (tri >= nt - r) { tri -= nt - r; ++r; }
        bx = r; by = r + tri;
    } else {
        bx = flat % gx;
        by = (flat / gx) % gy;
        bz = flat / (gx * gy);
    }

    const _Float16* Ab = A  + (size_t)bz * strideA;
    const _Float16* Bb = Bm + (size_t)bz * strideB;
    const int m0 = bx * 128;
    const int n0 = by * 128;

    const int tid  = threadIdx.x;
    const int lane = tid & 63;
    const int wv   = tid >> 6;
    const int wr   = (tid >> 7) & 1;
    const int wc   = (tid >> 6) & 1;
    const int fr   = lane & 15;
    const int hi   = lane >> 4;

    const int srow = tid >> 3;
    const int sk   = ((tid & 7) ^ (srow & 7)) * 8;

    const _Float16* gA0 = Ab + (size_t)(m0 + srow) * K + sk;
    const _Float16* gB0 = Bb + (size_t)(n0 + srow) * K + sk;
    _Float16* lA = &sA[(wv * 8) * BK];
    _Float16* lB = &sB[(wv * 8) * BK];

    const int ch0 = ((0 * 4 + hi) ^ (fr & 7)) * 8;
    const int ch1 = ((1 * 4 + hi) ^ (fr & 7)) * 8;
    const _Float16* fA = &sA[(wr * 64 + fr) * BK];
    const _Float16* fB = &sB[(wc * 64 + fr) * BK];

    floatx4 acc[4][4] = {};

    for (int k0 = 0; k0 < K; k0 += BK) {
        __syncthreads();
        #pragma unroll
        for (int p = 0; p < 4; ++p) {
            gload_lds16(gA0 + (size_t)(p * 32) * K + k0, lA + p * 32 * BK);
            gload_lds16(gB0 + (size_t)(p * 32) * K + k0, lB + p * 32 * BK);
        }
        __syncthreads();
        #pragma unroll
        for (int sub = 0; sub < 2; ++sub) {
            const int ch = (sub == 0) ? ch0 : ch1;
            half8 af[4], bf[4];
            #pragma unroll
            for (int i = 0; i < 4; ++i) af[i] = *(const half8*)(fA + i * 16 * BK + ch);
            #pragma unroll
            for (int j = 0; j < 4; ++j) bf[j] = *(const half8*)(fB + j * 16 * BK + ch);
            #pragma unroll
            for (int i = 0; i < 4; ++i)
                #pragma unroll
                for (int j = 0; j < 4; ++j)
                    acc[i][j] = __builtin_amdgcn_mfma_f32_16x16x32_f16(af[i], bf[j], acc[i][j], 0, 0, 0);
        }
    }

    float beta = 0.0f;
    const _Float16* Hb = nullptr;
    if (EPI == 1) { beta = beta_ptr[0]; Hb = Hm + (size_t)bz * strideH; }
    OutT* Cb = Cm + (size_t)bz * strideC;

    const bool mirror = TRI && (bx != by);
    if (mirror) __syncthreads();

    #pragma unroll
    for (int i = 0; i < 4; ++i) {
        const int rowb = m0 + wr * 64 + i * 16 + (hi << 2);
        #pragma unroll
        for (int j = 0; j < 4; ++j) {
            const int col = n0 + wc * 64 + j * 16 + fr;
            half4v mv;
            #pragma unroll
            for (int r = 0; r < 4; ++r) {
                size_t idx = (size_t)(rowb + r) * Ncols + col;
                float v = acc[i][j][r];
                if (EPI == 1) v = beta * v + (float)Hb[idx];
                Cb[idx] = (OutT)v;
                if (TRI) mv[r] = (_Float16)v;
            }
            if (mirror) {
                const int cl = wc * 64 + j * 16 + fr;
                const int rl = wr * 64 + i * 16 + (hi << 2);
                *(half4v*)(smem + cl * TP + rl) = mv;
            }
        }
    }

    if (mirror) {
        __syncthreads();
        #pragma unroll
        for (int k = 0; k < 8; ++k) {
            const int fl = tid + 256 * k;
            const int rr = fl >> 4;
            const int cc = (fl & 15) * 8;
            half8 v = *(const half8*)(smem + rr * TP + cc);
            *(half8*)((_Float16*)(void*)Cb + (size_t)(n0 + rr) * Ncols + m0 + cc) = v;
        }
    }

    if (EPI == 2) {
        const int p = ((bz * gy + by) << 1) + wc;
        #pragma unroll
        for (int i = 0; i < 4; ++i) {
            #pragma unroll
            for (int r = 0; r < 4; ++r) {
                float s = 0.f, ss2 = 0.f;
                #pragma unroll
                for (int j = 0; j < 4; ++j) {
                    float v = acc[i][j][r];
                    s += v; ss2 += v * v;
                }
                #pragma unroll
                for (int o = 1; o < 16; o <<= 1) {
                    s   += __shfl_xor(s,   o, 64);
                    ss2 += __shfl_xor(ss2, o, 64);
                }
                if (fr == 0) {
                    const int d = m0 + wr * 64 + i * 16 + (hi << 2) + r;
                    const size_t slot = (size_t)d * NSLOTS + p;
                    st_s[slot]  = s;
                    st_ss[slot] = ss2;
                }
            }
        }
    }
}

// ---------------------------------------------------------------------------
// 256x256 8-PHASE NT GEMM (PV only). R10's race-free schedule (passed
// refcheck) MINUS the per-phase sched_barrier(0) order-pinning (m141 failure
// mode). One sched_barrier remains per phase, before the stage-issue, to
// prevent gload_lds hoisting above earlier reads of its dest region
// (s_barrier is not a compiler fence); vm/lgkm asm "memory" clobbers fence
// the arrival side. Staging map (iter i: a=2i@buf0, b=2i+1@buf1, c=2i+2,
// d=2i+3): p1 Ah1(b),Bh0(b) | p2 Bh1(b) | p3 Ah0(c) | p4 vmcnt(2|0) |
// p5 Ah1(c),Bh0(c) | p6 Bh1(c) | p7 Ah0(d) | p8 vmcnt(2|0).
// half h = staging passes {h, h+2} (rows 0-63&128-191 / 64-127&192-255).
// ---------------------------------------------------------------------------
#define PHASE8(BUF, MH, KS, STAGES, VM)                                              \
    {                                                                                 \
        const _Float16* fA_ = &sA8[BUF][(wr8 * 128 + (MH) * 64 + fr) * BK8];          \
        const _Float16* fB_ = &sB8[BUF][(wc8 * 64 + fr) * BK8];                       \
        const int ch_ = (((KS) * 4 + hi) ^ (fr & 7)) * 8;                             \
        half8 af_[4], bf_[4];                                                         \
        _Pragma("unroll")                                                             \
        for (int m_ = 0; m_ < 4; ++m_) af_[m_] = *(const half8*)(fA_ + m_ * 16 * BK8 + ch_); \
        _Pragma("unroll")                                                             \
        for (int n_ = 0; n_ < 4; ++n_) bf_[n_] = *(const half8*)(fB_ + n_ * 16 * BK8 + ch_); \
        __builtin_amdgcn_sched_barrier(0);                                            \
        STAGES;                                                                       \
        __builtin_amdgcn_s_barrier();                                                 \
        asm volatile("s_waitcnt lgkmcnt(0)" ::: "memory");                            \
        __builtin_amdgcn_s_setprio(1);                                                \
        _Pragma("unroll")                                                             \
        for (int m_ = 0; m_ < 4; ++m_)                                                \
            _Pragma("unroll")                                                         \
            for (int n_ = 0; n_ < 4; ++n_)                                            \
                acc[(MH) * 4 + m_][n_] = __builtin_amdgcn_mfma_f32_16x16x32_f16(      \
                    af_[m_], bf_[n_], acc[(MH) * 4 + m_][n_], 0, 0, 0);               \
        __builtin_amdgcn_s_setprio(0);                                                \
        if ((VM) == 0)      asm volatile("s_waitcnt vmcnt(0)" ::: "memory");          \
        else if ((VM) == 2) asm volatile("s_waitcnt vmcnt(2)" ::: "memory");          \
        __builtin_amdgcn_s_barrier();                                                 \
    }

__global__ __launch_bounds__(512)
void gemm_nt256_pv(const _Float16* __restrict__ A, size_t strideA,
                   const _Float16* __restrict__ Bm, size_t strideB,
                   float* __restrict__ Cm, size_t strideC,
                   int M, int Ncols, int K,
                   const float* __restrict__ beta_ptr,
                   const _Float16* __restrict__ Hm, size_t strideH)
{
    constexpr int BK8 = 64;
    __shared__ _Float16 sA8[2][256 * BK8];
    __shared__ _Float16 sB8[2][256 * BK8];

    const int gx = gridDim.x, gy = gridDim.y;
    const int nwg = gx * gy * gridDim.z;
    int flat = blockIdx.x + gx * (blockIdx.y + gy * blockIdx.z);
    const int q8 = nwg >> 3;
    flat = (flat & 7) * q8 + (flat >> 3);
    const int bx = flat % gx;
    const int by = (flat / gx) % gy;
    const int bz = flat / (gx * gy);

    const _Float16* Ab = A  + (size_t)bz * strideA;
    const _Float16* Bb = Bm + (size_t)bz * strideB;
    const int m0 = bx * 256;
    const int n0 = by * 256;

    const int tid  = threadIdx.x;
    const int lane = tid & 63;
    const int wid  = tid >> 6;
    const int wr8  = wid >> 2;                  // 0..1
    const int wc8  = wid & 3;                   // 0..3
    const int fr   = lane & 15;
    const int hi   = lane >> 4;

    const int srow = (wid << 3) + (lane >> 3);
    const int sk   = ((lane & 7) ^ (srow & 7)) * 8;

    const _Float16* gA = Ab + (size_t)(m0 + srow) * K + sk;
    const _Float16* gB = Bb + (size_t)(n0 + srow) * K + sk;
    const int ldsbase = (wid << 3) * BK8;

    auto stageA = [&](int buf, int kt, int half) {
        const size_t ko = (size_t)kt * BK8;
        #pragma unroll
        for (int p = half; p < 4; p += 2)
            gload_lds16(gA + ko + (size_t)(p * 64) * K, &sA8[buf][ldsbase + p * 64 * BK8]);
    };
    auto stageB = [&](int buf, int kt, int half) {
        const size_t ko = (size_t)kt * BK8;
        #pragma unroll
        for (int p = half; p < 4; p += 2)
            gload_lds16(gB + ko + (size_t)(p * 64) * K, &sB8[buf][ldsbase + p * 64 * BK8]);
    };

    floatx4 acc[8][4] = {};

    const int nt = K / BK8;                     // 32 (PV)
    const int niter = nt >> 1;

    stageA(0, 0, 0); stageA(0, 0, 1);
    stageB(0, 0, 0); stageB(0, 0, 1);
    stageA(1, 1, 0);
    asm volatile("s_waitcnt vmcnt(2)" ::: "memory");
    __builtin_amdgcn_s_barrier();

    for (int it = 0; it < niter; ++it) {
        const int b = 2 * it + 1, c = 2 * it + 2, d = 2 * it + 3;
        const bool lastc = (c >= nt);
        const int vm_end = lastc ? 0 : 2;
        PHASE8(0, 0, 0, { stageA(1, b, 1); stageB(1, b, 0); }, -1)   // p1
        PHASE8(0, 0, 1, { stageB(1, b, 1); }, -1)                    // p2
        PHASE8(0, 1, 0, { if (!lastc) stageA(0, c, 0); }, -1)        // p3
        PHASE8(0, 1, 1, {}, vm_end)                                  // p4
        PHASE8(1, 0, 0, { if (!lastc) { stageA(0, c, 1); stageB(0, c, 0); } }, -1) // p5
        PHASE8(1, 0, 1, { if (!lastc) stageB(0, c, 1); }, -1)        // p6
        PHASE8(1, 1, 0, { if (!lastc) stageA(1, d, 0); }, -1)        // p7
        PHASE8(1, 1, 1, {}, vm_end)                                  // p8
    }

    const float beta = beta_ptr[0];
    const _Float16* Hb = Hm + (size_t)bz * strideH;
    float* Cb = Cm + (size_t)bz * strideC;

    #pragma unroll
    for (int i = 0; i < 8; ++i) {
        const int rowb = m0 + wr8 * 128 + i * 16 + (hi << 2);
        #pragma unroll
        for (int j = 0; j < 4; ++j) {
            const int col = n0 + wc8 * 64 + j * 16 + fr;
            #pragma unroll
            for (int r = 0; r < 4; ++r) {
                size_t idx = (size_t)(rowb + r) * Ncols + col;
                Cb[idx] = beta * acc[i][j][r] + (float)Hb[idx];
            }
        }
    }
}

// ---------------------------------------------------------------------------
// x [B,C,N] f32 -> xT [B,N,C] f16 (32x32 LDS tile transpose).
// z-slice B_DIM additionally converts W [D,C] f32 -> f16 (folded convert_w).
__global__ void transpose_convert_x(const float* __restrict__ x, _Float16* __restrict__ xT,
                                    const float* __restrict__ W, _Float16* __restrict__ Wh)
{
    const int bz = blockIdx.z;
    const int tx = threadIdx.x, ty = threadIdx.y;
    if (bz == B_DIM) {
        const int bid = blockIdx.x + blockIdx.y * gridDim.x;
        const int idx = bid * 256 + ty * 32 + tx;
        if (idx < D_DIM * C_DIM) Wh[idx] = (_Float16)W[idx];
        return;
    }
    __shared__ float tile[32][33];
    const int n0 = blockIdx.x * 32;
    const int c0 = blockIdx.y * 32;
    const float* xb = x + (size_t)bz * C_DIM * N_DIM;
    #pragma unroll
    for (int j = 0; j < 4; ++j)
        tile[ty + j * 8][tx] = xb[(size_t)(c0 + ty + j * 8) * N_DIM + n0 + tx];
    __syncthreads();
    _Float16* xtb = xT + (size_t)bz * N_DIM * C_DIM;
    #pragma unroll
    for (int j = 0; j < 4; ++j)
        xtb[(size_t)(n0 + ty + j * 8) * C_DIM + c0 + tx] = (_Float16)tile[tx][ty + j * 8];
}

// finalize BN stats: one block per channel, coalesced [d][p] reads (R15-verified ~5us).
__global__ __launch_bounds__(256)
void bn_finalize(const float* __restrict__ st_s, const float* __restrict__ st_ss,
                 const float* __restrict__ gamma, const float* __restrict__ bn_beta,
                 float2* __restrict__ stats)
{
    const int d = blockIdx.x;
    const int tid = threadIdx.x;
    const float* ps = st_s  + (size_t)d * NSLOTS;
    const float* pq = st_ss + (size_t)d * NSLOTS;
    float s  = ps[tid] + ps[tid + 256];
    float ss = pq[tid] + pq[tid + 256];
    #pragma unroll
    for (int o = 32; o; o >>= 1) {
        s  += __shfl_down(s,  o, 64);
        ss += __shfl_down(ss, o, 64);
    }
    __shared__ float red[8];
    const int wv = tid >> 6;
    if ((tid & 63) == 0) { red[wv] = s; red[4 + wv] = ss; }
    __syncthreads();
    if (tid == 0) {
        s  = red[0] + red[1] + red[2] + red[3];
        ss = red[4] + red[5] + red[6] + red[7];
        const float inv = 1.0f / (float)(B_DIM * N_DIM);
        float mean = s * inv;
        float var  = ss * inv - mean * mean;
        float scale = gamma[d] * rsqrtf(var + 1e-5f);
        stats[d] = make_float2(scale, bn_beta[d] - mean * scale);
    }
}

// mish(x) = x * tanh(softplus(x)) == x * ((1+e^x)^2 - 1) / ((1+e^x)^2 + 1)
__device__ __forceinline__ float mishf(float v)
{
    float t = __expf(fminf(v, 30.0f));
    float u = 1.0f + t;
    u *= u;
    return v * (u - 1.0f) * __builtin_amdgcn_rcpf(u + 1.0f);
}

// q [B,D,N] f16 -> h [B,D,N] f16  and  hT [B,N,D] f16 (BN + mish fused, tiled transpose)
__global__ void bn_mish(const _Float16* __restrict__ q, const float2* __restrict__ stats,
                        _Float16* __restrict__ h, _Float16* __restrict__ hT)
{
    __shared__ float tile[32][33];
    const int bz = blockIdx.z;
    const int n0 = blockIdx.x * 32;
    const int d0 = blockIdx.y * 32;
    const int tx = threadIdx.x, ty = threadIdx.y;
    const _Float16* qb = q + (size_t)bz * D_DIM * N_DIM;
    _Float16* hb = h + (size_t)bz * D_DIM * N_DIM;
    #pragma unroll
    for (int j = 0; j < 4; ++j) {
        int d = d0 + ty + j * 8;
        float2 sc = stats[d];
        float v  = (float)qb[(size_t)d * N_DIM + n0 + tx];
        float hv = mishf(v * sc.x + sc.y);
        tile[ty + j * 8][tx] = hv;
        hb[(size_t)d * N_DIM + n0 + tx] = (_Float16)hv;
    }
    __syncthreads();
    _Float16* htb = hT + (size_t)bz * N_DIM * D_DIM;
    #pragma unroll
    for (int j = 0; j < 4; ++j)
        htb[(size_t)(n0 + ty + j * 8) * D_DIM + d0 + tx] = (_Float16)tile[tx][ty + j * 8];
}

// row softmax: one row per WAVE (4 rows/block), no LDS, no barriers. In-place safe.
__global__ __launch_bounds__(256)
void softmax_rows(const _Float16* __restrict__ energy, size_t strideE,
                  _Float16* __restrict__ attn, size_t strideAt)
{
    const int wid  = threadIdx.x >> 6;
    const int lane = threadIdx.x & 63;
    const int n = blockIdx.x * 4 + wid;
    const int b = blockIdx.y;
    const _Float16* row = energy + (size_t)b * strideE + (size_t)n * N_DIM;
    _Float16*      orow = attn   + (size_t)b * strideAt + (size_t)n * N_DIM;
    float f[32];
    #pragma unroll
    for (int w = 0; w < 4; ++w) {
        half8 v = *(const half8*)(row + w * 512 + lane * 8);
        #pragma unroll
        for (int j = 0; j < 8; ++j) f[w * 8 + j] = (float)v[j];
    }
    float mx = f[0];
    #pragma unroll
    for (int k = 1; k < 32; ++k) mx = fmaxf(mx, f[k]);
    #pragma unroll
    for (int off = 1; off < 64; off <<= 1) mx = fmaxf(mx, __shfl_xor(mx, off, 64));
    float s = 0.f;
    #pragma unroll
    for (int k = 0; k < 32; ++k) { f[k] = __expf(f[k] - mx); s += f[k]; }
    #pragma unroll
    for (int off = 1; off < 64; off <<= 1) s += __shfl_xor(s, off, 64);
    const float inv = 1.0f / s;
    #pragma unroll
    for (int w = 0; w < 4; ++w) {
        half8 o;
        #pragma unroll
        for (int j = 0; j < 8; ++j) o[j] = (_Float16)(f[w * 8 + j] * inv);
        *(half8*)(orow + w * 512 + lane * 8) = o;
    }
}

// ---------------------------------------------------------------------------
extern "C" void kernel_launch(void* const* d_in, const int* in_sizes, int n_in,
                              void* d_out, int out_size, void* d_ws, size_t ws_size,
                              hipStream_t stream)
{
    const float* x       = (const float*)d_in[0];
    const float* W       = (const float*)d_in[1];
    const float* gamma   = (const float*)d_in[2];
    const float* bn_beta = (const float*)d_in[3];
    const float* beta    = (const float*)d_in[4];
    float* out = (float*)d_out;

    char* ws = (char*)d_ws;
    size_t off = 0;
    auto take = [&](size_t bytes) -> char* {
        char* p = ws + off;
        off = (off + bytes + 255) & ~(size_t)255;
        return p;
    };

    _Float16* xT    = (_Float16*)take((size_t)B_DIM * N_DIM * C_DIM * 2);  // aliased as hT later
    _Float16* q     = (_Float16*)take((size_t)B_DIM * D_DIM * N_DIM * 2);
    _Float16* h     = (_Float16*)take((size_t)B_DIM * D_DIM * N_DIM * 2);
    _Float16* Wh    = (_Float16*)take((size_t)D_DIM * C_DIM * 2);
    float2*   stats = (float2*)  take((size_t)D_DIM * sizeof(float2));
    float*    st_s  = (float*)   take((size_t)NSLOTS * D_DIM * 4);
    float*    st_ss = (float*)   take((size_t)NSLOTS * D_DIM * 4);
    _Float16* hT    = xT;                                                   // xT dead after GEMM1

    const size_t eSz = (size_t)N_DIM * N_DIM * 2;   // fp16 energy per batch (softmax in-place)
    const size_t fixedEnd = off;
    const int full = (ws_size >= fixedEnd + (size_t)B_DIM * eSz + 1024) ? 1 : 0;
    _Float16* energy = (_Float16*)take(full ? (size_t)B_DIM * eSz : eSz);
    _Float16* attn   = energy;                      // in-place softmax

    const int NT = N_DIM / 128;                     // 16
    const int TRI_BLOCKS = NT * (NT + 1) / 2;       // 136

    // 1. x -> xT f16 [B,N,C]  (+ folded W -> f16 on z-slice B_DIM)
    transpose_convert_x<<<dim3(N_DIM / 32, C_DIM / 32, B_DIM + 1), dim3(32, 8), 0, stream>>>(
        x, xT, W, Wh);
    // 2. q[b] = W @ x[b] : A=Wh [D,C], B=xT[b] [N,C]. EPI=2: fused BN partials.
    gemm_nt<2, 0, _Float16><<<dim3(D_DIM / 128, N_DIM / 128, B_DIM), dim3(256), 0, stream>>>(
        Wh, 0, xT, (size_t)N_DIM * C_DIM, q, (size_t)D_DIM * N_DIM,
        D_DIM, N_DIM, C_DIM, nullptr, nullptr, 0, st_s, st_ss);
    // 3. finalize BN stats (one block per channel)
    bn_finalize<<<dim3(D_DIM), dim3(256), 0, stream>>>(st_s, st_ss, gamma, bn_beta, stats);
    // 4. h = mish(BN(q)) : h [B,D,N] f16 + hT [B,N,D] f16
    bn_mish<<<dim3(N_DIM / 32, D_DIM / 32, B_DIM), dim3(32, 8), 0, stream>>>(q, stats, h, hT);

    if (full) {
        // 5. energy[b] = hT[b] @ hT[b]^T  f16, symmetric: triangle + coalesced mirror
        gemm_nt<0, 1, _Float16><<<dim3(TRI_BLOCKS, 1, B_DIM), dim3(256), 0, stream>>>(
            hT, (size_t)N_DIM * D_DIM, hT, (size_t)N_DIM * D_DIM,
            energy, (size_t)N_DIM * N_DIM, N_DIM, N_DIM, D_DIM,
            nullptr, nullptr, 0, nullptr, nullptr);
        // 6. attn = row-softmax(energy), in place
        softmax_rows<<<dim3(N_DIM / 4, B_DIM), dim3(256), 0, stream>>>(
            energy, (size_t)N_DIM * N_DIM, attn, (size_t)N_DIM * N_DIM);
        // 7. out = beta*(h @ attn^T) + h   (256^2 8-phase, K=2048)
        gemm_nt256_pv<<<dim3(D_DIM / 256, N_DIM / 256, B_DIM), dim3(512), 0, stream>>>(
            h, (size_t)D_DIM * N_DIM, attn, (size_t)N_DIM * N_DIM,
            out, (size_t)D_DIM * N_DIM, D_DIM, N_DIM, N_DIM,
            beta, h, (size_t)D_DIM * N_DIM);
    } else {
        for (int b = 0; b < B_DIM; ++b) {
            const _Float16* hTb = hT + (size_t)b * N_DIM * D_DIM;
            const _Float16* hb  = h  + (size_t)b * D_DIM * N_DIM;
            gemm_nt<0, 1, _Float16><<<dim3(TRI_BLOCKS, 1, 1), dim3(256), 0, stream>>>(
                hTb, 0, hTb, 0, energy, 0, N_DIM, N_DIM, D_DIM,
                nullptr, nullptr, 0, nullptr, nullptr);
            softmax_rows<<<dim3(N_DIM / 4, 1), dim3(256), 0, stream>>>(energy, 0, attn, 0);
            gemm_nt256_pv<<<dim3(D_DIM / 256, N_DIM / 256, 1), dim3(512), 0, stream>>>(
                hb, 0, attn, 0, out + (size_t)b * D_DIM * N_DIM, 0,
                D_DIM, N_DIM, N_DIM, beta, hb, 0);
        }
    }
}

// Round 19
// 229.358 us; speedup vs baseline: 1.0528x; 1.0528x over previous
//
#include <hip/hip_runtime.h>
#include <cstdint>
#include <cstddef>

#define B_DIM 16
#define C_DIM 512
#define D_DIM 512
#define N_DIM 2048
#define NSLOTS 512   // BN partial slots per channel: (bz, by, wc) = 16*16*2

typedef _Float16 half8  __attribute__((ext_vector_type(8)));
typedef _Float16 half4v __attribute__((ext_vector_type(4)));
typedef float    floatx4 __attribute__((ext_vector_type(4)));

__device__ __forceinline__ void gload_lds16(const _Float16* g, _Float16* l)
{
    // async global->LDS, 16B per lane. LDS dest = wave-uniform base + lane*16 (linear).
    __builtin_amdgcn_global_load_lds((const __attribute__((address_space(1))) void*)g,
                                     (__attribute__((address_space(3))) void*)l,
                                     16, 0, 0);
}

// ---------------------------------------------------------------------------
// NT GEMM: C[M,Ncols] = A[M,K] (f16 rm) * B[Ncols,K]^T (f16 rm)
// R4/R11-verified math/staging: 128x128 tile, BK=64, 4 waves (2x2), 4x4
// 16x16x32 MFMA frags, 2 k-subs/step, T2 XOR-chunk swizzle (BANK_CONFLICT=0),
// T1 XCD-chunked bijective block swizzle (nwg % 8 == 0 for all our grids).
// R18 lesson: 256^2 8-phase loses to this structure here (3x tested) —
// occupancy (2+ blocks/CU wave overlap, m114) beats pipeline depth at
// this problem's shapes. This structure is final.
// EPI==1: C = beta*acc + (float)H.
// EPI==2: plain store + per-block BN partials [d][p], p=(bz*gy+by)*2+wc
//   (R15-verified race-free + finalize-coalesced).
// TRI==1: symmetric C, 136 triangle tiles + coalesced LDS-transposed mirror
//   (R12-verified; needs the larger 34816 B smem).
// ---------------------------------------------------------------------------
template<int EPI, int TRI, typename OutT>
__global__ __launch_bounds__(256, 4)
void gemm_nt(const _Float16* __restrict__ A, size_t strideA,
             const _Float16* __restrict__ Bm, size_t strideB,
             OutT* __restrict__ Cm, size_t strideC,
             int M, int Ncols, int K,
             const float* __restrict__ beta_ptr,
             const _Float16* __restrict__ Hm, size_t strideH,
             float* __restrict__ st_s, float* __restrict__ st_ss)
{
    constexpr int BK  = 64;                     // halfs per staging row (128 B)
    constexpr int TP  = 136;                    // transpose-tile row pitch (halfs)
    constexpr int SMEM_HALFS = TRI ? (128 * TP) : (128 * 2 * BK);  // 34816 B / 32768 B
    __shared__ _Float16 smem[SMEM_HALFS];
    _Float16* sA = smem;                        // [128][64] halfs
    _Float16* sB = smem + 128 * BK;             // [128][64] halfs

    // --- T1: XCD-chunked bijective block swizzle ---
    const int gx = gridDim.x, gy = gridDim.y;
    const int nwg = gx * gy * gridDim.z;
    int flat = blockIdx.x + gx * (blockIdx.y + gy * blockIdx.z);
    const int q8 = nwg >> 3;
    flat = (flat & 7) * q8 + (flat >> 3);

    int bx, by, bz;
    if (TRI) {
        int tri = flat % gx;                    // gy == 1 in TRI launches
        bz = flat / gx;
        const int nt = Ncols >> 7;              // 16 tiles per side
        int r = 0;
        while (tri >= nt - r) { tri -= nt - r; ++r; }
        bx = r; by = r + tri;                   // by >= bx
    } else {
        bx = flat % gx;
        by = (flat / gx) % gy;
        bz = flat / (gx * gy);
    }

    const _Float16* Ab = A  + (size_t)bz * strideA;
    const _Float16* Bb = Bm + (size_t)bz * strideB;

    const int m0 = bx * 128;
    const int n0 = by * 128;

    const int tid  = threadIdx.x;
    const int lane = tid & 63;
    const int wv   = tid >> 6;
    const int wr   = (tid >> 7) & 1;            // wave row (2x2 waves, 64x64 out each)
    const int wc   = (tid >> 6) & 1;            // wave col
    const int fr   = lane & 15;
    const int hi   = lane >> 4;

    // staging: pass p covers 32 rows; lane row = p*32 + (tid>>3), chunk = tid&7.
    // Source chunk pre-swizzled: ck_src = (tid&7) ^ (row&7).
    const int srow = tid >> 3;
    const int sk   = ((tid & 7) ^ (srow & 7)) * 8;

    const _Float16* gA0 = Ab + (size_t)(m0 + srow) * K + sk;
    const _Float16* gB0 = Bb + (size_t)(n0 + srow) * K + sk;
    _Float16* lA = &sA[(wv * 8) * BK];          // wave-uniform LDS bases (linear dest)
    _Float16* lB = &sB[(wv * 8) * BK];

    // fragment chunk indices (row&7 == fr&7 for all frags)
    const int ch0 = ((0 * 4 + hi) ^ (fr & 7)) * 8;
    const int ch1 = ((1 * 4 + hi) ^ (fr & 7)) * 8;
    const _Float16* fA = &sA[(wr * 64 + fr) * BK];
    const _Float16* fB = &sB[(wc * 64 + fr) * BK];

    floatx4 acc[4][4] = {};

    for (int k0 = 0; k0 < K; k0 += BK) {
        __syncthreads();
        #pragma unroll
        for (int p = 0; p < 4; ++p) {
            gload_lds16(gA0 + (size_t)(p * 32) * K + k0, lA + p * 32 * BK);
            gload_lds16(gB0 + (size_t)(p * 32) * K + k0, lB + p * 32 * BK);
        }
        __syncthreads();
        #pragma unroll
        for (int sub = 0; sub < 2; ++sub) {
            const int ch = (sub == 0) ? ch0 : ch1;
            half8 af[4], bf[4];
            #pragma unroll
            for (int i = 0; i < 4; ++i) af[i] = *(const half8*)(fA + i * 16 * BK + ch);
            #pragma unroll
            for (int j = 0; j < 4; ++j) bf[j] = *(const half8*)(fB + j * 16 * BK + ch);
            #pragma unroll
            for (int i = 0; i < 4; ++i)
                #pragma unroll
                for (int j = 0; j < 4; ++j)
                    acc[i][j] = __builtin_amdgcn_mfma_f32_16x16x32_f16(af[i], bf[j], acc[i][j], 0, 0, 0);
        }
    }

    float beta = 0.0f;
    const _Float16* Hb = nullptr;
    if (EPI == 1) { beta = beta_ptr[0]; Hb = Hm + (size_t)bz * strideH; }
    OutT* Cb = Cm + (size_t)bz * strideC;

    const bool mirror = TRI && (bx != by);
    if (mirror) __syncthreads();                // staging LDS reads done; safe to reuse smem

    // C/D layout: col = lane&15, row = (lane>>4)*4 + r
    #pragma unroll
    for (int i = 0; i < 4; ++i) {
        const int rowb = m0 + wr * 64 + i * 16 + (hi << 2);
        #pragma unroll
        for (int j = 0; j < 4; ++j) {
            const int col = n0 + wc * 64 + j * 16 + fr;
            half4v mv;
            #pragma unroll
            for (int r = 0; r < 4; ++r) {
                size_t idx = (size_t)(rowb + r) * Ncols + col;
                float v = acc[i][j][r];
                if (EPI == 1) v = beta * v + (float)Hb[idx];
                Cb[idx] = (OutT)v;
                if (TRI) mv[r] = (_Float16)v;
            }
            if (mirror) {
                const int cl = wc * 64 + j * 16 + fr;            // 0..127
                const int rl = wr * 64 + i * 16 + (hi << 2);     // 0..127
                *(half4v*)(smem + cl * TP + rl) = mv;
            }
        }
    }

    if (mirror) {
        __syncthreads();                         // transpose tile complete
        #pragma unroll
        for (int k = 0; k < 8; ++k) {
            const int fl = tid + 256 * k;        // 0..2047 chunks of half8
            const int rr = fl >> 4;              // 0..127
            const int cc = (fl & 15) * 8;        // 0..120
            half8 v = *(const half8*)(smem + rr * TP + cc);
            *(half8*)((_Float16*)(void*)Cb + (size_t)(n0 + rr) * Ncols + m0 + cc) = v;
        }
    }

    if (EPI == 2) {
        // per-channel (row) BN partials, slot layout [d][p], p = (bz*gy+by)*2+wc.
        const int p = ((bz * gy + by) << 1) + wc;
        #pragma unroll
        for (int i = 0; i < 4; ++i) {
            #pragma unroll
            for (int r = 0; r < 4; ++r) {
                float s = 0.f, ss2 = 0.f;
                #pragma unroll
                for (int j = 0; j < 4; ++j) {
                    float v = acc[i][j][r];
                    s += v; ss2 += v * v;
                }
                #pragma unroll
                for (int o = 1; o < 16; o <<= 1) {
                    s   += __shfl_xor(s,   o, 64);
                    ss2 += __shfl_xor(ss2, o, 64);
                }
                if (fr == 0) {
                    const int d = m0 + wr * 64 + i * 16 + (hi << 2) + r;
                    const size_t slot = (size_t)d * NSLOTS + p;
                    st_s[slot]  = s;
                    st_ss[slot] = ss2;
                }
            }
        }
    }
}

// ---------------------------------------------------------------------------
// x [B,C,N] f32 -> xT [B,N,C] f16 (32x32 LDS tile transpose).
// z-slice B_DIM additionally converts W [D,C] f32 -> f16 (folded convert_w).
__global__ void transpose_convert_x(const float* __restrict__ x, _Float16* __restrict__ xT,
                                    const float* __restrict__ W, _Float16* __restrict__ Wh)
{
    const int bz = blockIdx.z;
    const int tx = threadIdx.x, ty = threadIdx.y;
    if (bz == B_DIM) {
        // W convert: 1024 blocks x 256 threads x 1 elem = 262144 = D*C
        const int bid = blockIdx.x + blockIdx.y * gridDim.x;
        const int idx = bid * 256 + ty * 32 + tx;
        if (idx < D_DIM * C_DIM) Wh[idx] = (_Float16)W[idx];
        return;
    }
    __shared__ float tile[32][33];
    const int n0 = blockIdx.x * 32;
    const int c0 = blockIdx.y * 32;
    const float* xb = x + (size_t)bz * C_DIM * N_DIM;
    #pragma unroll
    for (int j = 0; j < 4; ++j)
        tile[ty + j * 8][tx] = xb[(size_t)(c0 + ty + j * 8) * N_DIM + n0 + tx];
    __syncthreads();
    _Float16* xtb = xT + (size_t)bz * N_DIM * C_DIM;
    #pragma unroll
    for (int j = 0; j < 4; ++j)
        xtb[(size_t)(n0 + ty + j * 8) * C_DIM + c0 + tx] = (_Float16)tile[tx][ty + j * 8];
}

// finalize BN stats: one block per channel, coalesced [d][p] reads (R15-verified ~5us).
__global__ __launch_bounds__(256)
void bn_finalize(const float* __restrict__ st_s, const float* __restrict__ st_ss,
                 const float* __restrict__ gamma, const float* __restrict__ bn_beta,
                 float2* __restrict__ stats)
{
    const int d = blockIdx.x;
    const int tid = threadIdx.x;
    const float* ps = st_s  + (size_t)d * NSLOTS;
    const float* pq = st_ss + (size_t)d * NSLOTS;
    float s  = ps[tid] + ps[tid + 256];
    float ss = pq[tid] + pq[tid + 256];
    #pragma unroll
    for (int o = 32; o; o >>= 1) {
        s  += __shfl_down(s,  o, 64);
        ss += __shfl_down(ss, o, 64);
    }
    __shared__ float red[8];
    const int wv = tid >> 6;
    if ((tid & 63) == 0) { red[wv] = s; red[4 + wv] = ss; }
    __syncthreads();
    if (tid == 0) {
        s  = red[0] + red[1] + red[2] + red[3];
        ss = red[4] + red[5] + red[6] + red[7];
        const float inv = 1.0f / (float)(B_DIM * N_DIM);
        float mean = s * inv;
        float var  = ss * inv - mean * mean;
        float scale = gamma[d] * rsqrtf(var + 1e-5f);
        stats[d] = make_float2(scale, bn_beta[d] - mean * scale);
    }
}

// mish(x) = x * tanh(softplus(x)) == x * ((1+e^x)^2 - 1) / ((1+e^x)^2 + 1)
__device__ __forceinline__ float mishf(float v)
{
    float t = __expf(fminf(v, 30.0f));
    float u = 1.0f + t;
    u *= u;
    return v * (u - 1.0f) * __builtin_amdgcn_rcpf(u + 1.0f);
}

// q [B,D,N] f16 -> h [B,D,N] f16  and  hT [B,N,D] f16 (BN + mish fused, tiled transpose)
__global__ void bn_mish(const _Float16* __restrict__ q, const float2* __restrict__ stats,
                        _Float16* __restrict__ h, _Float16* __restrict__ hT)
{
    __shared__ float tile[32][33];
    const int bz = blockIdx.z;
    const int n0 = blockIdx.x * 32;
    const int d0 = blockIdx.y * 32;
    const int tx = threadIdx.x, ty = threadIdx.y;
    const _Float16* qb = q + (size_t)bz * D_DIM * N_DIM;
    _Float16* hb = h + (size_t)bz * D_DIM * N_DIM;
    #pragma unroll
    for (int j = 0; j < 4; ++j) {
        int d = d0 + ty + j * 8;
        float2 sc = stats[d];
        float v  = (float)qb[(size_t)d * N_DIM + n0 + tx];
        float hv = mishf(v * sc.x + sc.y);
        tile[ty + j * 8][tx] = hv;
        hb[(size_t)d * N_DIM + n0 + tx] = (_Float16)hv;
    }
    __syncthreads();
    _Float16* htb = hT + (size_t)bz * N_DIM * D_DIM;
    #pragma unroll
    for (int j = 0; j < 4; ++j)
        htb[(size_t)(n0 + ty + j * 8) * D_DIM + d0 + tx] = (_Float16)tile[tx][ty + j * 8];
}

// row softmax: one row per WAVE (4 rows/block), no LDS, no barriers. In-place safe.
__global__ __launch_bounds__(256)
void softmax_rows(const _Float16* __restrict__ energy, size_t strideE,
                  _Float16* __restrict__ attn, size_t strideAt)
{
    const int wid  = threadIdx.x >> 6;
    const int lane = threadIdx.x & 63;
    const int n = blockIdx.x * 4 + wid;
    const int b = blockIdx.y;
    const _Float16* row = energy + (size_t)b * strideE + (size_t)n * N_DIM;
    _Float16*      orow = attn   + (size_t)b * strideAt + (size_t)n * N_DIM;
    float f[32];
    #pragma unroll
    for (int w = 0; w < 4; ++w) {
        half8 v = *(const half8*)(row + w * 512 + lane * 8);
        #pragma unroll
        for (int j = 0; j < 8; ++j) f[w * 8 + j] = (float)v[j];
    }
    float mx = f[0];
    #pragma unroll
    for (int k = 1; k < 32; ++k) mx = fmaxf(mx, f[k]);
    #pragma unroll
    for (int off = 1; off < 64; off <<= 1) mx = fmaxf(mx, __shfl_xor(mx, off, 64));
    float s = 0.f;
    #pragma unroll
    for (int k = 0; k < 32; ++k) { f[k] = __expf(f[k] - mx); s += f[k]; }
    #pragma unroll
    for (int off = 1; off < 64; off <<= 1) s += __shfl_xor(s, off, 64);
    const float inv = 1.0f / s;
    #pragma unroll
    for (int w = 0; w < 4; ++w) {
        half8 o;
        #pragma unroll
        for (int j = 0; j < 8; ++j) o[j] = (_Float16)(f[w * 8 + j] * inv);
        *(half8*)(orow + w * 512 + lane * 8) = o;
    }
}

// ---------------------------------------------------------------------------
extern "C" void kernel_launch(void* const* d_in, const int* in_sizes, int n_in,
                              void* d_out, int out_size, void* d_ws, size_t ws_size,
                              hipStream_t stream)
{
    const float* x       = (const float*)d_in[0];
    const float* W       = (const float*)d_in[1];
    const float* gamma   = (const float*)d_in[2];
    const float* bn_beta = (const float*)d_in[3];
    const float* beta    = (const float*)d_in[4];
    float* out = (float*)d_out;

    char* ws = (char*)d_ws;
    size_t off = 0;
    auto take = [&](size_t bytes) -> char* {
        char* p = ws + off;
        off = (off + bytes + 255) & ~(size_t)255;
        return p;
    };

    _Float16* xT    = (_Float16*)take((size_t)B_DIM * N_DIM * C_DIM * 2);  // aliased as hT later
    _Float16* q     = (_Float16*)take((size_t)B_DIM * D_DIM * N_DIM * 2);
    _Float16* h     = (_Float16*)take((size_t)B_DIM * D_DIM * N_DIM * 2);
    _Float16* Wh    = (_Float16*)take((size_t)D_DIM * C_DIM * 2);
    float2*   stats = (float2*)  take((size_t)D_DIM * sizeof(float2));
    float*    st_s  = (float*)   take((size_t)NSLOTS * D_DIM * 4);
    float*    st_ss = (float*)   take((size_t)NSLOTS * D_DIM * 4);
    _Float16* hT    = xT;                                                   // xT dead after GEMM1

    const size_t eSz = (size_t)N_DIM * N_DIM * 2;   // fp16 energy per batch (softmax in-place)
    const size_t fixedEnd = off;
    const int full = (ws_size >= fixedEnd + (size_t)B_DIM * eSz + 1024) ? 1 : 0;
    _Float16* energy = (_Float16*)take(full ? (size_t)B_DIM * eSz : eSz);
    _Float16* attn   = energy;                      // in-place softmax

    const int NT = N_DIM / 128;                     // 16
    const int TRI_BLOCKS = NT * (NT + 1) / 2;       // 136

    // 1. x -> xT f16 [B,N,C]  (+ folded W -> f16 on z-slice B_DIM)
    transpose_convert_x<<<dim3(N_DIM / 32, C_DIM / 32, B_DIM + 1), dim3(32, 8), 0, stream>>>(
        x, xT, W, Wh);
    // 2. q[b] = W @ x[b] : A=Wh [D,C], B=xT[b] [N,C]. EPI=2: fused BN partials.
    gemm_nt<2, 0, _Float16><<<dim3(D_DIM / 128, N_DIM / 128, B_DIM), dim3(256), 0, stream>>>(
        Wh, 0, xT, (size_t)N_DIM * C_DIM, q, (size_t)D_DIM * N_DIM,
        D_DIM, N_DIM, C_DIM, nullptr, nullptr, 0, st_s, st_ss);
    // 3. finalize BN stats (one block per channel)
    bn_finalize<<<dim3(D_DIM), dim3(256), 0, stream>>>(st_s, st_ss, gamma, bn_beta, stats);
    // 4. h = mish(BN(q)) : h [B,D,N] f16 + hT [B,N,D] f16
    bn_mish<<<dim3(N_DIM / 32, D_DIM / 32, B_DIM), dim3(32, 8), 0, stream>>>(q, stats, h, hT);

    if (full) {
        // 5. energy[b] = hT[b] @ hT[b]^T  f16, symmetric: triangle + coalesced mirror
        gemm_nt<0, 1, _Float16><<<dim3(TRI_BLOCKS, 1, B_DIM), dim3(256), 0, stream>>>(
            hT, (size_t)N_DIM * D_DIM, hT, (size_t)N_DIM * D_DIM,
            energy, (size_t)N_DIM * N_DIM, N_DIM, N_DIM, D_DIM,
            nullptr, nullptr, 0, nullptr, nullptr);
        // 6. attn = row-softmax(energy), in place
        softmax_rows<<<dim3(N_DIM / 4, B_DIM), dim3(256), 0, stream>>>(
            energy, (size_t)N_DIM * N_DIM, attn, (size_t)N_DIM * N_DIM);
        // 7. out = beta*(h @ attn^T) + h
        gemm_nt<1, 0, float><<<dim3(D_DIM / 128, N_DIM / 128, B_DIM), dim3(256), 0, stream>>>(
            h, (size_t)D_DIM * N_DIM, attn, (size_t)N_DIM * N_DIM,
            out, (size_t)D_DIM * N_DIM, D_DIM, N_DIM, N_DIM,
            beta, h, (size_t)D_DIM * N_DIM, nullptr, nullptr);
    } else {
        for (int b = 0; b < B_DIM; ++b) {
            const _Float16* hTb = hT + (size_t)b * N_DIM * D_DIM;
            const _Float16* hb  = h  + (size_t)b * D_DIM * N_DIM;
            gemm_nt<0, 1, _Float16><<<dim3(TRI_BLOCKS, 1, 1), dim3(256), 0, stream>>>(
                hTb, 0, hTb, 0, energy, 0, N_DIM, N_DIM, D_DIM,
                nullptr, nullptr, 0, nullptr, nullptr);
            softmax_rows<<<dim3(N_DIM / 4, 1), dim3(256), 0, stream>>>(energy, 0, attn, 0);
            gemm_nt<1, 0, float><<<dim3(D_DIM / 128, N_DIM / 128, 1), dim3(256), 0, stream>>>(
                hb, 0, attn, 0, out + (size_t)b * D_DIM * N_DIM, 0,
                D_DIM, N_DIM, N_DIM, beta, hb, 0, nullptr, nullptr);
        }
    }
}